// Round 5
// baseline (162.746 us; speedup 1.0000x reference)
//
#include <hip/hip_runtime.h>

#define NPTS 8192      // H*W
#define BCLS 4         // C
#define NP   6         // B*(C-1) pairs
#define R2   9.0f
#define RAD  3.0f
#define GRD  64
#define NCELL (GRD*GRD)

#define ST_U 0
#define ST_A 1
#define ST_D 2

// ---------------------------------------------------------------------------
// One block per (batch, class) pair. Phases:
//  P0 zero: global sums (by candidate id), LDS cell counts, st, output slice.
//  P1 compact: argmax class, ballot-compact candidates into LDS (asc. pixel).
//  P2 bbox reduce -> square grid, cell = max(6, span/63) >= 2*RAD.
//  P3 grid build: count / scan / scatter (all LDS).
//  P4 greedy-NMS fixed point: pending i rescans its <=2x2 cell window; dies on
//     an ALIVE earlier neighbor, lives when all earlier neighbors decided
//     non-alive. Monotone, terminates (least pending index always resolves),
//     bit-identical to the sequential greedy (same _rn arithmetic).
//  P5 assignment: nearest ALIVE center in the window (== global argmin: any
//     alive outside has d2 > 9 > suppressor's d2; kept -> self at d2=0),
//     tie j<bj == jnp first-index; atomic f32 accumulate by candidate id.
//  P6 output: kept candidates overwrite the zero-filled slice.
// ---------------------------------------------------------------------------
__global__ __launch_bounds__(1024) void k_fused(
    const float* __restrict__ seg, const float* __restrict__ lidar,
    float* __restrict__ sumx, float* __restrict__ sumy, float* __restrict__ cntw,
    float* __restrict__ out)
{
    const int p = blockIdx.x;
    const int b = p / 3, cls = p % 3 + 1;
    const int tid = threadIdx.x, lane = tid & 63, wv = tid >> 6;
    const int base = p * NPTS;

    __shared__ float2 sp[NPTS];                 // 64 KB candidate coords
    __shared__ unsigned short cidx[NPTS];       // 16 KB candidate -> pixel n
    __shared__ unsigned short sortid[NPTS];     // 16 KB grid-sorted candidate ids
    __shared__ unsigned int cellcnt[NCELL];     // 16 KB
    __shared__ unsigned int cellstart[NCELL];   // 16 KB
    __shared__ unsigned char st[NPTS];          //  8 KB
    __shared__ unsigned long long ballots[128]; //  1 KB (8 chunks x 16 waves)
    __shared__ unsigned int base128[128];       // 512 B
    __shared__ unsigned int wtot[16];
    __shared__ float redbuf[4][16];
    __shared__ float sbminx, sbminy, scell;
    __shared__ int sM;

    float* ok = out + (size_t)2 * NP * NPTS + base;   // keep slice for pair p

    // ---- P0: zeroing (no deps; out-slice zero overlapped here) ----
    for (int k = tid; k < NPTS; k += 1024) {
        st[k] = ST_U;
        sumx[base + k] = 0.f; sumy[base + k] = 0.f; cntw[base + k] = 0.f;
        ok[k] = 0.f;
    }
    {
        float2* oc = (float2*)(out + (size_t)2 * base);
        for (int k = tid; k < NPTS; k += 1024) oc[k] = make_float2(0.f, 0.f);
    }
    for (int k = tid; k < NCELL; k += 1024) cellcnt[k] = 0u;

    // ---- P1: argmax + ballot compaction ----
    const float* segb = seg + (size_t)b * BCLS * NPTS;
    const float* lx = lidar + (size_t)b * 2 * NPTS;
    const float* ly = lx + NPTS;
    for (int c0 = 0; c0 < 8; ++c0) {
        int n = c0 * 1024 + tid;
        float bv = segb[n];
        int bc = 0;
        #pragma unroll
        for (int c2 = 1; c2 < BCLS; ++c2) {
            float v = segb[c2 * NPTS + n];
            if (v > bv) { bv = v; bc = c2; }   // strict >: first index wins ties
        }
        unsigned long long bal = __ballot(bc == cls);
        if (lane == 0) ballots[c0 * 16 + wv] = bal;
    }
    __syncthreads();
    if (tid == 0) {
        unsigned int acc = 0;
        for (int q = 0; q < 128; ++q) { base128[q] = acc; acc += __popcll(ballots[q]); }
        sM = (int)acc;
    }
    __syncthreads();
    const int M = sM;
    for (int c0 = 0; c0 < 8; ++c0) {
        unsigned long long bal = ballots[c0 * 16 + wv];
        if ((bal >> lane) & 1ull) {
            int n = c0 * 1024 + tid;
            int pos = (int)base128[c0 * 16 + wv] + __popcll(bal & ((1ull << lane) - 1ull));
            sp[pos] = make_float2(lx[n], ly[n]);
            cidx[pos] = (unsigned short)n;
        }
    }
    __syncthreads();

    // ---- P2: bbox -> grid geometry ----
    {
        float mnx = 3e38f, mxx = -3e38f, mny = 3e38f, mxy = -3e38f;
        for (int i = tid; i < M; i += 1024) {
            float2 q = sp[i];
            mnx = fminf(mnx, q.x); mxx = fmaxf(mxx, q.x);
            mny = fminf(mny, q.y); mxy = fmaxf(mxy, q.y);
        }
        for (int d = 32; d; d >>= 1) {
            mnx = fminf(mnx, __shfl_xor(mnx, d, 64));
            mxx = fmaxf(mxx, __shfl_xor(mxx, d, 64));
            mny = fminf(mny, __shfl_xor(mny, d, 64));
            mxy = fmaxf(mxy, __shfl_xor(mxy, d, 64));
        }
        if (lane == 0) { redbuf[0][wv] = mnx; redbuf[1][wv] = mxx;
                         redbuf[2][wv] = mny; redbuf[3][wv] = mxy; }
    }
    __syncthreads();
    if (tid == 0) {
        float a = redbuf[0][0], b2 = redbuf[1][0], c = redbuf[2][0], d = redbuf[3][0];
        for (int q = 1; q < 16; ++q) {
            a = fminf(a, redbuf[0][q]); b2 = fmaxf(b2, redbuf[1][q]);
            c = fminf(c, redbuf[2][q]); d = fmaxf(d, redbuf[3][q]);
        }
        sbminx = a; sbminy = c;
        scell = fmaxf(2.0f * RAD, fmaxf(b2 - a, d - c) / 63.0f);
    }
    __syncthreads();
    const float bminx = sbminx, bminy = sbminy, inv = 1.0f / scell;

    // ---- P3: grid count / scan / scatter ----
    for (int i = tid; i < M; i += 1024) {
        float2 q = sp[i];
        int ix = min(GRD - 1, max(0, (int)((q.x - bminx) * inv)));
        int iy = min(GRD - 1, max(0, (int)((q.y - bminy) * inv)));
        atomicAdd(&cellcnt[iy * GRD + ix], 1u);
    }
    __syncthreads();
    {
        unsigned int c4[4], t4 = 0;
        #pragma unroll
        for (int q = 0; q < 4; ++q) { c4[q] = cellcnt[tid * 4 + q]; t4 += c4[q]; }
        unsigned int v = t4;
        for (int d = 1; d < 64; d <<= 1) {
            unsigned int u = __shfl_up(v, d, 64);
            if (lane >= d) v += u;
        }
        if (lane == 63) wtot[wv] = v;
        __syncthreads();
        if (tid == 0) {
            unsigned int acc = 0;
            for (int q = 0; q < 16; ++q) { unsigned int t = wtot[q]; wtot[q] = acc; acc += t; }
        }
        __syncthreads();
        unsigned int excl = wtot[wv] + v - t4;
        #pragma unroll
        for (int q = 0; q < 4; ++q) {
            cellstart[tid * 4 + q] = excl; excl += c4[q];
            cellcnt[tid * 4 + q] = 0u;         // reset for scatter pass
        }
    }
    __syncthreads();
    for (int i = tid; i < M; i += 1024) {
        float2 q = sp[i];
        int ix = min(GRD - 1, max(0, (int)((q.x - bminx) * inv)));
        int iy = min(GRD - 1, max(0, (int)((q.y - bminy) * inv)));
        int c = iy * GRD + ix;
        unsigned int pos = cellstart[c] + atomicAdd(&cellcnt[c], 1u);
        sortid[pos] = (unsigned short)i;       // cellcnt restored to true counts
    }
    __syncthreads();

    // ---- P4: fixed-point greedy NMS (all-LDS rounds) ----
    unsigned int pend = 0;
    for (int k = 0; k < 8; ++k)
        if ((k << 10) + tid < M) pend |= 1u << k;
    for (int round = 0; round < NPTS; ++round) {
        unsigned int np = 0;
        for (int k = 0; k < 8; ++k) {
            if (!(pend & (1u << k))) continue;
            int i = tid + (k << 10);
            float2 me = sp[i];
            int cx0 = max(0, (int)((me.x - RAD - bminx) * inv));
            int cx1 = min(GRD - 1, (int)((me.x + RAD - bminx) * inv));
            int cy0 = max(0, (int)((me.y - RAD - bminy) * inv));
            int cy1 = min(GRD - 1, (int)((me.y + RAD - bminy) * inv));
            bool dead = false, undec = false;
            for (int cy = cy0; cy <= cy1 && !dead; ++cy)
                for (int cx = cx0; cx <= cx1 && !dead; ++cx) {
                    int c = cy * GRD + cx;
                    unsigned int e0 = cellstart[c], e1 = e0 + cellcnt[c];
                    for (unsigned int e = e0; e < e1; ++e) {
                        int j = sortid[e];
                        if (j >= i) continue;          // only earlier can suppress
                        unsigned char sv = st[j];
                        if (sv == ST_D) continue;      // dead is final
                        float2 q = sp[j];
                        float dx = __fsub_rn(me.x, q.x), dy = __fsub_rn(me.y, q.y);
                        float d2 = __fadd_rn(__fmul_rn(dx, dx), __fmul_rn(dy, dy));
                        if (d2 < R2) {
                            if (sv == ST_A) { dead = true; break; }
                            undec = true;              // stale-U read: conservative
                        }
                    }
                }
            if (dead) st[i] = ST_D;
            else if (!undec) st[i] = ST_A;
            else np |= 1u << k;
        }
        pend = np;
        if (__syncthreads_count(pend != 0) == 0) break;
    }

    // ---- P5: assignment + accumulation (by candidate id) ----
    for (int i = tid; i < M; i += 1024) {
        float2 me = sp[i];
        int bj;
        if (st[i] == ST_A) {
            bj = i;                                    // self: unique d2 = 0
        } else {
            int cx0 = max(0, (int)((me.x - RAD - bminx) * inv));
            int cx1 = min(GRD - 1, (int)((me.x + RAD - bminx) * inv));
            int cy0 = max(0, (int)((me.y - RAD - bminy) * inv));
            int cy1 = min(GRD - 1, (int)((me.y + RAD - bminy) * inv));
            float bd = 3e38f;
            bj = -1;
            for (int cy = cy0; cy <= cy1; ++cy)
                for (int cx = cx0; cx <= cx1; ++cx) {
                    int c = cy * GRD + cx;
                    unsigned int e0 = cellstart[c], e1 = e0 + cellcnt[c];
                    for (unsigned int e = e0; e < e1; ++e) {
                        int j = sortid[e];
                        if (st[j] != ST_A) continue;
                        float2 q = sp[j];
                        float dx = __fsub_rn(me.x, q.x), dy = __fsub_rn(me.y, q.y);
                        float d2 = __fadd_rn(__fmul_rn(dx, dx), __fmul_rn(dy, dy));
                        if (d2 < bd || (d2 == bd && j < bj)) { bd = d2; bj = j; }
                    }
                }
            if (bj < 0) continue;                      // impossible when M > 0
        }
        atomicAdd(&sumx[base + bj], me.x);
        atomicAdd(&sumy[base + bj], me.y);
        atomicAdd(&cntw[base + bj], 1.0f);
    }
    __syncthreads();   // drains the atomics (vmcnt) before readback

    // ---- P6: kept candidates overwrite the zeroed output slice ----
    for (int i = tid; i < M; i += 1024) {
        if (st[i] != ST_A) continue;
        int n = cidx[i];
        float c = cntw[base + i];                      // >= 1 (self-assign)
        out[2 * (base + n)]     = sumx[base + i] / c;  // == sums/max(cnt,1)
        out[2 * (base + n) + 1] = sumy[base + i] / c;
        ok[n] = 1.0f;
    }
}

// ---------------------------------------------------------------------------
extern "C" void kernel_launch(void* const* d_in, const int* in_sizes, int n_in,
                              void* d_out, int out_size, void* d_ws, size_t ws_size,
                              hipStream_t stream) {
    const float* seg   = (const float*)d_in[0];   // [B,C,H,W] f32
    const float* lidar = (const float*)d_in[1];   // [B,2,H,W] f32
    float* out = (float*)d_out;

    const size_t A = (size_t)NP * NPTS;           // 49152
    float* sumx = (float*)d_ws;                   // 4A
    float* sumy = sumx + A;                       // 4A
    float* cntw = sumy + A;                       // 4A   (total ws: 576 KB)

    k_fused<<<NP, 1024, 0, stream>>>(seg, lidar, sumx, sumy, cntw, out);
}

// Round 6
// 117.752 us; speedup vs baseline: 1.3821x; 1.3821x over previous
//
#include <hip/hip_runtime.h>

#define NPTS 8192      // H*W
#define BCLS 4         // C
#define NP   6         // B*(C-1) pairs
#define R2   9.0f
#define RAD  3.0f
#define GRD  64
#define NCELL (GRD*GRD)
#define PCAP 4096      // pending-list capacity per buffer (overflow -> sweep fallback)

#define ST_U 0
#define ST_A 1
#define ST_D 2

// ---------------------------------------------------------------------------
// One block per (batch, class) pair. Phases:
//  P0 zero   P1 argmax+ballot-compact   P2 bbox->grid geom
//  P3 grid build (packed start<<16|cnt)
//  P4 greedy-NMS fixed point: round-0 sweep + pending-list rounds; branchless
//     window scans (no early break -> pipelined LDS loads). Monotone U->{A,D},
//     least pending index always resolves -> terminates; decisions bit-match
//     the sequential greedy (same _rn arithmetic, strict <).
//  P5 assignment: nearest ALIVE in <=2x2-cell window (== global argmin: any
//     alive outside has d2>9>suppressor's; self at d2=0), tie j<bj = jnp
//     first-index; global f32 atomics by candidate id.
//  P6 kept candidates overwrite the zero-filled output slice.
// ---------------------------------------------------------------------------
__global__ __launch_bounds__(1024) void k_fused(
    const float* __restrict__ seg, const float* __restrict__ lidar,
    float* __restrict__ sumx, float* __restrict__ sumy, float* __restrict__ cntw,
    float* __restrict__ out)
{
    const int p = blockIdx.x;
    const int b = p / 3, cls = p % 3 + 1;
    const int tid = threadIdx.x, lane = tid & 63, wv = tid >> 6;
    const int base = p * NPTS;

    __shared__ float2 sp[NPTS];                 // 64 KB candidate coords
    __shared__ unsigned short cidx[NPTS];       // 16 KB candidate -> pixel n
    __shared__ unsigned short sortid[NPTS];     // 16 KB grid-sorted candidate ids
    __shared__ unsigned int cellpack[NCELL];    // 16 KB start<<16 | cnt
    __shared__ unsigned char st[NPTS];          //  8 KB
    __shared__ unsigned short plist[2][PCAP];   // 16 KB pending lists
    __shared__ int pcnt[2];
    __shared__ unsigned long long ballots[128]; //  1 KB
    __shared__ unsigned int base128[128];       // 512 B
    __shared__ unsigned int wtot[16];
    __shared__ float redbuf[4][16];
    __shared__ float sbminx, sbminy, scell;
    __shared__ int sM;

    float* ok = out + (size_t)2 * NP * NPTS + base;   // keep slice for pair p

    // ---- P0: zeroing ----
    for (int k = tid; k < NPTS; k += 1024) {
        st[k] = ST_U;
        sumx[base + k] = 0.f; sumy[base + k] = 0.f; cntw[base + k] = 0.f;
        ok[k] = 0.f;
    }
    {
        float2* oc = (float2*)(out + (size_t)2 * base);
        for (int k = tid; k < NPTS; k += 1024) oc[k] = make_float2(0.f, 0.f);
    }
    for (int k = tid; k < NCELL; k += 1024) cellpack[k] = 0u;
    if (tid == 0) { pcnt[0] = 0; pcnt[1] = 0; }

    // ---- P1: argmax + ballot compaction ----
    const float* segb = seg + (size_t)b * BCLS * NPTS;
    const float* lx = lidar + (size_t)b * 2 * NPTS;
    const float* ly = lx + NPTS;
    for (int c0 = 0; c0 < 8; ++c0) {
        int n = c0 * 1024 + tid;
        float bv = segb[n];
        int bc = 0;
        #pragma unroll
        for (int c2 = 1; c2 < BCLS; ++c2) {
            float v = segb[c2 * NPTS + n];
            if (v > bv) { bv = v; bc = c2; }   // strict >: first index wins ties
        }
        unsigned long long bal = __ballot(bc == cls);
        if (lane == 0) ballots[c0 * 16 + wv] = bal;
    }
    __syncthreads();
    if (tid == 0) {
        unsigned int acc = 0;
        for (int q = 0; q < 128; ++q) { base128[q] = acc; acc += __popcll(ballots[q]); }
        sM = (int)acc;
    }
    __syncthreads();
    const int M = sM;
    for (int c0 = 0; c0 < 8; ++c0) {
        unsigned long long bal = ballots[c0 * 16 + wv];
        if ((bal >> lane) & 1ull) {
            int n = c0 * 1024 + tid;
            int pos = (int)base128[c0 * 16 + wv] + __popcll(bal & ((1ull << lane) - 1ull));
            sp[pos] = make_float2(lx[n], ly[n]);
            cidx[pos] = (unsigned short)n;
        }
    }
    __syncthreads();

    // ---- P2: bbox -> grid geometry ----
    {
        float mnx = 3e38f, mxx = -3e38f, mny = 3e38f, mxy = -3e38f;
        for (int i = tid; i < M; i += 1024) {
            float2 q = sp[i];
            mnx = fminf(mnx, q.x); mxx = fmaxf(mxx, q.x);
            mny = fminf(mny, q.y); mxy = fmaxf(mxy, q.y);
        }
        for (int d = 32; d; d >>= 1) {
            mnx = fminf(mnx, __shfl_xor(mnx, d, 64));
            mxx = fmaxf(mxx, __shfl_xor(mxx, d, 64));
            mny = fminf(mny, __shfl_xor(mny, d, 64));
            mxy = fmaxf(mxy, __shfl_xor(mxy, d, 64));
        }
        if (lane == 0) { redbuf[0][wv] = mnx; redbuf[1][wv] = mxx;
                         redbuf[2][wv] = mny; redbuf[3][wv] = mxy; }
    }
    __syncthreads();
    if (tid == 0) {
        float a = redbuf[0][0], b2 = redbuf[1][0], c = redbuf[2][0], d = redbuf[3][0];
        for (int q = 1; q < 16; ++q) {
            a = fminf(a, redbuf[0][q]); b2 = fmaxf(b2, redbuf[1][q]);
            c = fminf(c, redbuf[2][q]); d = fmaxf(d, redbuf[3][q]);
        }
        sbminx = a; sbminy = c;
        scell = fmaxf(2.0f * RAD, fmaxf(b2 - a, d - c) / 63.0f);
    }
    __syncthreads();
    const float bminx = sbminx, bminy = sbminy, inv = 1.0f / scell;

    // ---- P3: grid count / scan / scatter (packed) ----
    for (int i = tid; i < M; i += 1024) {
        float2 q = sp[i];
        int ix = min(GRD - 1, max(0, (int)((q.x - bminx) * inv)));
        int iy = min(GRD - 1, max(0, (int)((q.y - bminy) * inv)));
        atomicAdd(&cellpack[iy * GRD + ix], 1u);
    }
    __syncthreads();
    {
        unsigned int c4[4], t4 = 0;
        #pragma unroll
        for (int q = 0; q < 4; ++q) { c4[q] = cellpack[tid * 4 + q]; t4 += c4[q]; }
        unsigned int v = t4;
        for (int d = 1; d < 64; d <<= 1) {
            unsigned int u = __shfl_up(v, d, 64);
            if (lane >= d) v += u;
        }
        if (lane == 63) wtot[wv] = v;
        __syncthreads();
        if (tid == 0) {
            unsigned int acc = 0;
            for (int q = 0; q < 16; ++q) { unsigned int t = wtot[q]; wtot[q] = acc; acc += t; }
        }
        __syncthreads();
        unsigned int excl = wtot[wv] + v - t4;
        #pragma unroll
        for (int q = 0; q < 4; ++q) {
            cellpack[tid * 4 + q] = excl << 16;    // start in high 16, count cleared
            excl += c4[q];
        }
    }
    __syncthreads();
    for (int i = tid; i < M; i += 1024) {
        float2 q = sp[i];
        int ix = min(GRD - 1, max(0, (int)((q.x - bminx) * inv)));
        int iy = min(GRD - 1, max(0, (int)((q.y - bminy) * inv)));
        unsigned int old = atomicAdd(&cellpack[iy * GRD + ix], 1u);
        sortid[(old >> 16) + (old & 0xffffu)] = (unsigned short)i;
    }   // cellpack now = start<<16 | cnt
    __syncthreads();

    // ---- P4: fixed-point greedy NMS (compacted pending, branchless scans) ----
    #define SCAN_WIN(I, ME, DEAD, UNDEC)                                          \
    {                                                                             \
        int cx0 = max(0, (int)((ME.x - RAD - bminx) * inv));                      \
        int cx1 = min(GRD - 1, (int)((ME.x + RAD - bminx) * inv));                \
        int cy0 = max(0, (int)((ME.y - RAD - bminy) * inv));                      \
        int cy1 = min(GRD - 1, (int)((ME.y + RAD - bminy) * inv));                \
        DEAD = false; UNDEC = false;                                              \
        for (int cy = cy0; cy <= cy1; ++cy)                                       \
            for (int cx = cx0; cx <= cx1; ++cx) {                                 \
                unsigned int w = cellpack[cy * GRD + cx];                         \
                unsigned int e0 = w >> 16, e1 = e0 + (w & 0xffffu);               \
                for (unsigned int e = e0; e < e1; ++e) {                          \
                    int j = sortid[e];                                            \
                    float2 q = sp[j];                                             \
                    unsigned char sv = st[j];                                     \
                    float dx = __fsub_rn(ME.x, q.x), dy = __fsub_rn(ME.y, q.y);   \
                    float d2 = __fadd_rn(__fmul_rn(dx, dx), __fmul_rn(dy, dy));   \
                    bool in = (d2 < R2) & (j < I);                                \
                    DEAD  |= in & (sv == ST_A);                                   \
                    UNDEC |= in & (sv == ST_U);                                   \
                }                                                                 \
            }                                                                     \
    }

    // round 0: full sweep, append pending
    for (int i = tid; i < M; i += 1024) {
        float2 me = sp[i];
        bool dead, undec;
        SCAN_WIN(i, me, dead, undec);
        if (dead) st[i] = ST_D;
        else if (!undec) st[i] = ST_A;
        else {
            int pos = atomicAdd(&pcnt[0], 1);
            if (pos < PCAP) plist[0][pos] = (unsigned short)i;
        }
    }
    __syncthreads();
    int cur = 0;
    for (int round = 0; round < NPTS; ++round) {
        int pc = pcnt[cur];
        if (pc == 0) break;
        if (pc > PCAP) {                       // overflow fallback: full sweeps
            for (;;) {
                bool any = false;
                __syncthreads();
                for (int i = tid; i < M; i += 1024) {
                    if (st[i] != ST_U) continue;
                    float2 me = sp[i];
                    bool dead, undec;
                    SCAN_WIN(i, me, dead, undec);
                    if (dead) st[i] = ST_D;
                    else if (!undec) st[i] = ST_A;
                    else any = true;
                }
                if (__syncthreads_count(any) == 0) break;
            }
            break;
        }
        if (tid == 0) pcnt[cur ^ 1] = 0;
        __syncthreads();
        for (int idx = tid; idx < pc; idx += 1024) {
            int i = plist[cur][idx];
            float2 me = sp[i];
            bool dead, undec;
            SCAN_WIN(i, me, dead, undec);
            if (dead) st[i] = ST_D;
            else if (!undec) st[i] = ST_A;
            else {
                int pos = atomicAdd(&pcnt[cur ^ 1], 1);
                if (pos < PCAP) plist[cur ^ 1][pos] = (unsigned short)i;
            }
        }
        __syncthreads();
        cur ^= 1;
    }

    // ---- P5: assignment + accumulation (branchless argmin over window) ----
    for (int i = tid; i < M; i += 1024) {
        float2 me = sp[i];
        int bj;
        if (st[i] == ST_A) {
            bj = i;                            // self: unique d2 = 0
        } else {
            int cx0 = max(0, (int)((me.x - RAD - bminx) * inv));
            int cx1 = min(GRD - 1, (int)((me.x + RAD - bminx) * inv));
            int cy0 = max(0, (int)((me.y - RAD - bminy) * inv));
            int cy1 = min(GRD - 1, (int)((me.y + RAD - bminy) * inv));
            float bd = 3e38f;
            bj = -1;
            for (int cy = cy0; cy <= cy1; ++cy)
                for (int cx = cx0; cx <= cx1; ++cx) {
                    unsigned int w = cellpack[cy * GRD + cx];
                    unsigned int e0 = w >> 16, e1 = e0 + (w & 0xffffu);
                    for (unsigned int e = e0; e < e1; ++e) {
                        int j = sortid[e];
                        float2 q = sp[j];
                        unsigned char sv = st[j];
                        float dx = __fsub_rn(me.x, q.x), dy = __fsub_rn(me.y, q.y);
                        float d2 = __fadd_rn(__fmul_rn(dx, dx), __fmul_rn(dy, dy));
                        bool better = (sv == ST_A) &
                                      ((d2 < bd) | ((d2 == bd) & (j < bj)));
                        bd = better ? d2 : bd;
                        bj = better ? j : bj;
                    }
                }
            if (bj < 0) continue;              // impossible when M > 0
        }
        atomicAdd(&sumx[base + bj], me.x);
        atomicAdd(&sumy[base + bj], me.y);
        atomicAdd(&cntw[base + bj], 1.0f);
    }
    __syncthreads();   // drain atomics before readback (validated round 5)

    // ---- P6: kept candidates overwrite the zeroed output slice ----
    for (int i = tid; i < M; i += 1024) {
        if (st[i] != ST_A) continue;
        int n = cidx[i];
        float c = cntw[base + i];              // >= 1 (self-assign)
        out[2 * (base + n)]     = sumx[base + i] / c;   // == sums/max(cnt,1)
        out[2 * (base + n) + 1] = sumy[base + i] / c;
        ok[n] = 1.0f;
    }
}

// ---------------------------------------------------------------------------
extern "C" void kernel_launch(void* const* d_in, const int* in_sizes, int n_in,
                              void* d_out, int out_size, void* d_ws, size_t ws_size,
                              hipStream_t stream) {
    const float* seg   = (const float*)d_in[0];   // [B,C,H,W] f32
    const float* lidar = (const float*)d_in[1];   // [B,2,H,W] f32
    float* out = (float*)d_out;

    const size_t A = (size_t)NP * NPTS;           // 49152
    float* sumx = (float*)d_ws;                   // 4A
    float* sumy = sumx + A;                       // 4A
    float* cntw = sumy + A;                       // 4A   (total ws: 576 KB)

    k_fused<<<NP, 1024, 0, stream>>>(seg, lidar, sumx, sumy, cntw, out);
}

// Round 7
// 109.502 us; speedup vs baseline: 1.4862x; 1.0753x over previous
//
#include <hip/hip_runtime.h>

#define NPTS 8192      // H*W
#define BCLS 4         // C
#define NP   6         // B*(C-1) pairs
#define R2   9.0f
#define RAD  3.0f
#define GRD  64
#define NCELL (GRD*GRD)
#define PCAP 2048      // pending-list capacity (overflow -> sweep fallback)
#define LDSK 2048      // LDS kept-center accumulator cap (overflow -> global)

#define ST_U 0
#define ST_A 1
#define ST_D 2

// ---------------------------------------------------------------------------
// One block per (batch, class) pair. Window scans exploit: cell >= 2*RAD so a
// radius-RAD window spans <= 2x2 cells, and a row's cells are contiguous in
// sortid => each scan = TWO flat [s,e) loops. All hot loops run in grid-sorted
// order (i = sortid[g]) so wave lanes are spatially coherent (broadcast LDS
// reads, similar trip counts). Kept-center sums accumulate in LDS by kept-rank
// (ballot bitmask + prefix), global arrays only as zero-on-demand fallback.
// Decisions are bit-identical to the sequential greedy (same _rn arithmetic,
// strict <, ascending-index tie-breaks, monotone U->{A,D} fixed point).
// ---------------------------------------------------------------------------
__global__ __launch_bounds__(1024) void k_fused(
    const float* __restrict__ seg, const float* __restrict__ lidar,
    float* __restrict__ sumx, float* __restrict__ sumy, float* __restrict__ cntw,
    float* __restrict__ out)
{
    const int p = blockIdx.x;
    const int b = p / 3, cls = p % 3 + 1;
    const int tid = threadIdx.x, lane = tid & 63, wv = tid >> 6;
    const int base = p * NPTS;

    __shared__ float2 sp[NPTS];                 // 64 KB
    __shared__ unsigned short cidx[NPTS];       // 16 KB candidate -> pixel
    __shared__ unsigned short sortid[NPTS];     // 16 KB grid order
    __shared__ unsigned int cellpack[NCELL];    // 16 KB start<<16 | cnt
    __shared__ unsigned char st[NPTS];          //  8 KB
    __shared__ unsigned short plist[2][PCAP];   //  8 KB
    __shared__ float ksx[LDSK], ksy[LDSK], kcn[LDSK];  // 24 KB
    __shared__ int pcnt[2];
    __shared__ unsigned long long ballots[128]; //  1 KB (mask words / kept words)
    __shared__ unsigned int base128[128];       // 512 B (prefix)
    __shared__ unsigned int wtot[16];
    __shared__ float redbuf[4][16];
    __shared__ float sbminx, sbminy, scell;
    __shared__ int sM, sK;

    float* ok = out + (size_t)2 * NP * NPTS + base;

    // ---- P0: zeroing (LDS + output slice; global sums zeroed on demand) ----
    for (int k = tid; k < NPTS; k += 1024) { st[k] = ST_U; ok[k] = 0.f; }
    {
        float2* oc = (float2*)(out + (size_t)2 * base);
        for (int k = tid; k < NPTS; k += 1024) oc[k] = make_float2(0.f, 0.f);
    }
    for (int k = tid; k < NCELL; k += 1024) cellpack[k] = 0u;
    for (int k = tid; k < LDSK; k += 1024) { ksx[k] = 0.f; ksy[k] = 0.f; kcn[k] = 0.f; }
    if (tid == 0) { pcnt[0] = 0; pcnt[1] = 0; }

    // ---- P1: argmax + ballot compaction ----
    const float* segb = seg + (size_t)b * BCLS * NPTS;
    const float* lx = lidar + (size_t)b * 2 * NPTS;
    const float* ly = lx + NPTS;
    for (int c0 = 0; c0 < 8; ++c0) {
        int n = c0 * 1024 + tid;
        float bv = segb[n];
        int bc = 0;
        #pragma unroll
        for (int c2 = 1; c2 < BCLS; ++c2) {
            float v = segb[c2 * NPTS + n];
            if (v > bv) { bv = v; bc = c2; }   // strict >: first index wins ties
        }
        unsigned long long bal = __ballot(bc == cls);
        if (lane == 0) ballots[c0 * 16 + wv] = bal;
    }
    __syncthreads();
    if (wv == 0) {                              // wave-scan of 128 popcounts
        unsigned int p0 = (unsigned int)__popcll(ballots[2 * lane]);
        unsigned int p1 = (unsigned int)__popcll(ballots[2 * lane + 1]);
        unsigned int s = p0 + p1, v = s;
        for (int d = 1; d < 64; d <<= 1) {
            unsigned int u = __shfl_up(v, d, 64);
            if (lane >= d) v += u;
        }
        base128[2 * lane] = v - s;
        base128[2 * lane + 1] = v - p1;
        if (lane == 63) sM = (int)v;
    }
    __syncthreads();
    const int M = sM;
    for (int c0 = 0; c0 < 8; ++c0) {
        unsigned long long bal = ballots[c0 * 16 + wv];
        if ((bal >> lane) & 1ull) {
            int n = c0 * 1024 + tid;
            int pos = (int)base128[c0 * 16 + wv] + __popcll(bal & ((1ull << lane) - 1ull));
            sp[pos] = make_float2(lx[n], ly[n]);
            cidx[pos] = (unsigned short)n;
        }
    }
    __syncthreads();

    // ---- P2: bbox -> grid geometry ----
    {
        float mnx = 3e38f, mxx = -3e38f, mny = 3e38f, mxy = -3e38f;
        for (int i = tid; i < M; i += 1024) {
            float2 q = sp[i];
            mnx = fminf(mnx, q.x); mxx = fmaxf(mxx, q.x);
            mny = fminf(mny, q.y); mxy = fmaxf(mxy, q.y);
        }
        for (int d = 32; d; d >>= 1) {
            mnx = fminf(mnx, __shfl_xor(mnx, d, 64));
            mxx = fmaxf(mxx, __shfl_xor(mxx, d, 64));
            mny = fminf(mny, __shfl_xor(mny, d, 64));
            mxy = fmaxf(mxy, __shfl_xor(mxy, d, 64));
        }
        if (lane == 0) { redbuf[0][wv] = mnx; redbuf[1][wv] = mxx;
                         redbuf[2][wv] = mny; redbuf[3][wv] = mxy; }
    }
    __syncthreads();
    if (tid == 0) {
        float a = redbuf[0][0], b2 = redbuf[1][0], c = redbuf[2][0], d = redbuf[3][0];
        for (int q = 1; q < 16; ++q) {
            a = fminf(a, redbuf[0][q]); b2 = fmaxf(b2, redbuf[1][q]);
            c = fminf(c, redbuf[2][q]); d = fmaxf(d, redbuf[3][q]);
        }
        sbminx = a; sbminy = c;
        scell = fmaxf(2.0f * RAD, fmaxf(b2 - a, d - c) / 63.0f);
    }
    __syncthreads();
    const float bminx = sbminx, bminy = sbminy, inv = 1.0f / scell;

    // ---- P3: grid count / scan / scatter (packed start<<16|cnt) ----
    for (int i = tid; i < M; i += 1024) {
        float2 q = sp[i];
        int ix = min(GRD - 1, max(0, (int)((q.x - bminx) * inv)));
        int iy = min(GRD - 1, max(0, (int)((q.y - bminy) * inv)));
        atomicAdd(&cellpack[iy * GRD + ix], 1u);
    }
    __syncthreads();
    {
        unsigned int c4[4], t4 = 0;
        #pragma unroll
        for (int q = 0; q < 4; ++q) { c4[q] = cellpack[tid * 4 + q]; t4 += c4[q]; }
        unsigned int v = t4;
        for (int d = 1; d < 64; d <<= 1) {
            unsigned int u = __shfl_up(v, d, 64);
            if (lane >= d) v += u;
        }
        if (lane == 63) wtot[wv] = v;
        __syncthreads();
        if (tid == 0) {
            unsigned int acc = 0;
            for (int q = 0; q < 16; ++q) { unsigned int t = wtot[q]; wtot[q] = acc; acc += t; }
        }
        __syncthreads();
        unsigned int excl = wtot[wv] + v - t4;
        #pragma unroll
        for (int q = 0; q < 4; ++q) { cellpack[tid * 4 + q] = excl << 16; excl += c4[q]; }
    }
    __syncthreads();
    for (int i = tid; i < M; i += 1024) {
        float2 q = sp[i];
        int ix = min(GRD - 1, max(0, (int)((q.x - bminx) * inv)));
        int iy = min(GRD - 1, max(0, (int)((q.y - bminy) * inv)));
        unsigned int old = atomicAdd(&cellpack[iy * GRD + ix], 1u);
        sortid[(old >> 16) + (old & 0xffffu)] = (unsigned short)i;
    }
    __syncthreads();

    // window rows: [s,e) over sortid, flat + branchless
    #define ROW_FLAGS(CY, CX0, CX1, I, ME, DEAD, UNDEC)                           \
    {                                                                             \
        unsigned int wa = cellpack[(CY) * GRD + (CX0)];                           \
        unsigned int wb = cellpack[(CY) * GRD + (CX1)];                           \
        unsigned int e0 = wa >> 16, e1 = (wb >> 16) + (wb & 0xffffu);             \
        for (unsigned int e = e0; e < e1; ++e) {                                  \
            int j = sortid[e];                                                    \
            float2 q = sp[j];                                                     \
            unsigned char sv = st[j];                                             \
            float dx = __fsub_rn(ME.x, q.x), dy = __fsub_rn(ME.y, q.y);           \
            float d2 = __fadd_rn(__fmul_rn(dx, dx), __fmul_rn(dy, dy));           \
            bool in = (d2 < R2) & (j < (I));                                      \
            DEAD  |= in & (sv == ST_A);                                           \
            UNDEC |= in & (sv == ST_U);                                           \
        }                                                                         \
    }
    #define SCAN_FLAGS(I, ME, DEAD, UNDEC)                                        \
    {                                                                             \
        int cx0 = max(0, (int)((ME.x - RAD - bminx) * inv));                      \
        int cx1 = min(GRD - 1, (int)((ME.x + RAD - bminx) * inv));                \
        int cy0 = max(0, (int)((ME.y - RAD - bminy) * inv));                      \
        int cy1 = min(GRD - 1, (int)((ME.y + RAD - bminy) * inv));                \
        DEAD = false; UNDEC = false;                                              \
        ROW_FLAGS(cy0, cx0, cx1, I, ME, DEAD, UNDEC);                             \
        if (cy1 > cy0) ROW_FLAGS(cy1, cx0, cx1, I, ME, DEAD, UNDEC);              \
    }

    // ---- P4 round 0: full sweep in grid order, wave-ordered pending append ----
    for (int g = tid; g < M; g += 1024) {
        int i = sortid[g];
        float2 me = sp[i];
        bool dead, undec;
        SCAN_FLAGS(i, me, dead, undec);
        if (dead) st[i] = ST_D;
        else if (!undec) st[i] = ST_A;
        bool pendf = !dead && undec;
        unsigned long long act = __ballot(true);
        unsigned long long bal = __ballot(pendf);
        int leader = __builtin_ctzll(act);
        int cnt = __popcll(bal);
        int wbase = 0;
        if (lane == leader && cnt) wbase = atomicAdd(&pcnt[0], cnt);
        wbase = __shfl(wbase, leader, 64);
        if (pendf) {
            int pos = wbase + __popcll(bal & ((1ull << lane) - 1ull));
            if (pos < PCAP) plist[0][pos] = (unsigned short)i;
        }
    }

    // ---- P4 rounds over compacted pending ----
    int cur = 0;
    for (int round = 0; round < NPTS; ++round) {
        __syncthreads();
        int pc = pcnt[cur];
        if (pc == 0) break;
        if (pc > PCAP) {                        // overflow fallback: full sweeps
            for (;;) {
                bool any = false;
                __syncthreads();
                for (int i = tid; i < M; i += 1024) {
                    if (st[i] != ST_U) continue;
                    float2 me = sp[i];
                    bool dead, undec;
                    SCAN_FLAGS(i, me, dead, undec);
                    if (dead) st[i] = ST_D;
                    else if (!undec) st[i] = ST_A;
                    else any = true;
                }
                if (__syncthreads_count(any) == 0) break;
            }
            break;
        }
        if (tid == 0) pcnt[cur ^ 1] = 0;
        __syncthreads();
        for (int idx = tid; idx < pc; idx += 1024) {
            int i = plist[cur][idx];
            float2 me = sp[i];
            bool dead, undec;
            SCAN_FLAGS(i, me, dead, undec);
            if (dead) st[i] = ST_D;
            else if (!undec) st[i] = ST_A;
            bool pendf = !dead && undec;
            unsigned long long act = __ballot(true);
            unsigned long long bal = __ballot(pendf);
            int leader = __builtin_ctzll(act);
            int cnt = __popcll(bal);
            int wbase = 0;
            if (lane == leader && cnt) wbase = atomicAdd(&pcnt[cur ^ 1], cnt);
            wbase = __shfl(wbase, leader, 64);
            if (pendf) {
                int pos = wbase + __popcll(bal & ((1ull << lane) - 1ull));
                if (pos < PCAP) plist[cur ^ 1][pos] = (unsigned short)i;
            }
        }
        cur ^= 1;
    }
    __syncthreads();

    // ---- kept-rank: ballot bitmask + wave-scanned prefix ----
    for (int k = 0; k < 8; ++k) {
        int i = (k << 10) + tid;
        unsigned long long bal = __ballot(st[i] == ST_A);  // st[i>=M] stays ST_U
        if (lane == 0) ballots[(k << 4) + wv] = bal;
    }
    __syncthreads();
    if (wv == 0) {
        unsigned int p0 = (unsigned int)__popcll(ballots[2 * lane]);
        unsigned int p1 = (unsigned int)__popcll(ballots[2 * lane + 1]);
        unsigned int s = p0 + p1, v = s;
        for (int d = 1; d < 64; d <<= 1) {
            unsigned int u = __shfl_up(v, d, 64);
            if (lane >= d) v += u;
        }
        base128[2 * lane] = v - s;
        base128[2 * lane + 1] = v - p1;
        if (lane == 63) sK = (int)v;
    }
    __syncthreads();
    #define KRANK(J) ((int)base128[(J) >> 6] +                                    \
                      __popcll(ballots[(J) >> 6] & ((1ull << ((J) & 63)) - 1ull)))
    if (sK > LDSK) {                            // cold fallback prep: zero globals
        for (int k = tid; k < NPTS; k += 1024) {
            sumx[base + k] = 0.f; sumy[base + k] = 0.f; cntw[base + k] = 0.f;
        }
        __syncthreads();
    }

    // ---- P5: assignment + LDS accumulation (grid order) ----
    #define ROW_ARGMIN(CY, CX0, CX1, ME, BD, BJ)                                  \
    {                                                                             \
        unsigned int wa = cellpack[(CY) * GRD + (CX0)];                           \
        unsigned int wb = cellpack[(CY) * GRD + (CX1)];                           \
        unsigned int e0 = wa >> 16, e1 = (wb >> 16) + (wb & 0xffffu);             \
        for (unsigned int e = e0; e < e1; ++e) {                                  \
            int j = sortid[e];                                                    \
            float2 q = sp[j];                                                     \
            unsigned char sv = st[j];                                             \
            float dx = __fsub_rn(ME.x, q.x), dy = __fsub_rn(ME.y, q.y);           \
            float d2 = __fadd_rn(__fmul_rn(dx, dx), __fmul_rn(dy, dy));           \
            bool better = (sv == ST_A) & ((d2 < BD) | ((d2 == BD) & (j < BJ)));   \
            BD = better ? d2 : BD;                                                \
            BJ = better ? j : BJ;                                                 \
        }                                                                         \
    }
    for (int g = tid; g < M; g += 1024) {
        int i = sortid[g];
        float2 me = sp[i];
        int bj;
        if (st[i] == ST_A) {
            bj = i;                              // self: unique d2 = 0
        } else {
            int cx0 = max(0, (int)((me.x - RAD - bminx) * inv));
            int cx1 = min(GRD - 1, (int)((me.x + RAD - bminx) * inv));
            int cy0 = max(0, (int)((me.y - RAD - bminy) * inv));
            int cy1 = min(GRD - 1, (int)((me.y + RAD - bminy) * inv));
            float bd = 3e38f;
            bj = -1;
            ROW_ARGMIN(cy0, cx0, cx1, me, bd, bj);
            if (cy1 > cy0) ROW_ARGMIN(cy1, cx0, cx1, me, bd, bj);
            if (bj < 0) continue;                // impossible when M > 0
        }
        int r = KRANK(bj);
        if (r < LDSK) {
            atomicAdd(&ksx[r], me.x);
            atomicAdd(&ksy[r], me.y);
            atomicAdd(&kcn[r], 1.0f);
        } else {                                 // cold fallback: global by cand id
            atomicAdd(&sumx[base + bj], me.x);
            atomicAdd(&sumy[base + bj], me.y);
            atomicAdd(&cntw[base + bj], 1.0f);
        }
    }
    __syncthreads();

    // ---- P6: kept candidates overwrite the zeroed output slice ----
    for (int i = tid; i < M; i += 1024) {
        if (st[i] != ST_A) continue;
        int n = cidx[i];
        int r = KRANK(i);
        float sx, sy, c;
        if (r < LDSK) { sx = ksx[r]; sy = ksy[r]; c = kcn[r]; }
        else { sx = sumx[base + i]; sy = sumy[base + i]; c = cntw[base + i]; }
        out[2 * (base + n)]     = sx / c;        // c >= 1 (self-assign)
        out[2 * (base + n) + 1] = sy / c;
        ok[n] = 1.0f;
    }
}

// ---------------------------------------------------------------------------
extern "C" void kernel_launch(void* const* d_in, const int* in_sizes, int n_in,
                              void* d_out, int out_size, void* d_ws, size_t ws_size,
                              hipStream_t stream) {
    const float* seg   = (const float*)d_in[0];   // [B,C,H,W] f32
    const float* lidar = (const float*)d_in[1];   // [B,2,H,W] f32
    float* out = (float*)d_out;

    const size_t A = (size_t)NP * NPTS;           // 49152
    float* sumx = (float*)d_ws;                   // 4A
    float* sumy = sumx + A;                       // 4A
    float* cntw = sumy + A;                       // 4A   (fallback only)

    k_fused<<<NP, 1024, 0, stream>>>(seg, lidar, sumx, sumy, cntw, out);
}